// Round 1
// baseline (1230.562 us; speedup 1.0000x reference)
//
#include <hip/hip_runtime.h>

// Problem constants
#define LSP  6272   // 8*28*28 spatial
#define LK   784    // 4*14*14 pooled spatial
#define CIN  512
#define CQ   64
#define CV   256
#define NB   4
#define QCHUNK 1568 // 6272/4 query chunk (49 tiles of 32)

// ---------------------------------------------------------------------------
// K1: QKV projection. out[o][p] = sum_c W[o][c] * x[n][c][p]
// Stacked rows: oy=0 -> Wq (64), oy=1 -> Wk (64), oy=2..5 -> Wv (4x64).
// Tiled fp32 GEMM: BM=64, BN=64, BK=32, 256 threads, 4x4 micro-tile.
// ---------------------------------------------------------------------------
__global__ __launch_bounds__(256) void qkv_kernel(
    const float* __restrict__ x, const float* __restrict__ Wq,
    const float* __restrict__ Wk, const float* __restrict__ Wv,
    float* __restrict__ qf, float* __restrict__ kfull, float* __restrict__ vfull)
{
    int t  = threadIdx.x;
    int p0 = blockIdx.x * 64;
    int oy = blockIdx.y;
    int n  = blockIdx.z;

    const float* Wsrc;
    float* dst;
    if (oy == 0)      { Wsrc = Wq;                   dst = qf    + (size_t)n*CQ*LSP; }
    else if (oy == 1) { Wsrc = Wk;                   dst = kfull + (size_t)n*CQ*LSP; }
    else              { Wsrc = Wv + (oy-2)*64*CIN;   dst = vfull + (size_t)n*CV*LSP + (size_t)(oy-2)*64*LSP; }

    __shared__ float As[32][64];   // [c][o]
    __shared__ float Bs[32][64];   // [c][p]
    int tx = t & 15, ty = t >> 4;
    float acc[4][4] = {};

    for (int kb = 0; kb < CIN; kb += 32) {
        #pragma unroll
        for (int i = 0; i < 8; i++) {          // A tile: 64x32
            int idx = i*256 + t;
            int cc = idx & 31, m = idx >> 5;
            As[cc][m] = Wsrc[(size_t)m*CIN + kb + cc];
        }
        #pragma unroll
        for (int i = 0; i < 8; i++) {          // B tile: 32x64
            int idx = i*256 + t;
            int j = idx & 63, cc = idx >> 6;
            Bs[cc][j] = x[((size_t)(n*CIN + kb + cc))*LSP + p0 + j];
        }
        __syncthreads();
        #pragma unroll
        for (int kk = 0; kk < 32; kk++) {
            float a[4], b[4];
            #pragma unroll
            for (int i = 0; i < 4; i++) a[i] = As[kk][ty*4+i];
            #pragma unroll
            for (int j = 0; j < 4; j++) b[j] = Bs[kk][tx*4+j];
            #pragma unroll
            for (int i = 0; i < 4; i++)
                #pragma unroll
                for (int j = 0; j < 4; j++)
                    acc[i][j] += a[i]*b[j];
        }
        __syncthreads();
    }
    #pragma unroll
    for (int i = 0; i < 4; i++)
        #pragma unroll
        for (int j = 0; j < 4; j++)
            dst[(size_t)(ty*4+i)*LSP + p0 + tx*4 + j] = acc[i][j];
}

// ---------------------------------------------------------------------------
// K2: 2x2x2 maxpool over (t,h,w): [nch][8][28][28] -> [nch][4][14][14]
// ---------------------------------------------------------------------------
__global__ void pool_kernel(const float* __restrict__ in, float* __restrict__ out, int nch)
{
    int id = blockIdx.x*256 + threadIdx.x;
    if (id >= nch*LK) return;
    int nc = id / LK, pp = id % LK;
    int tp = pp / 196, rem = pp % 196, hp = rem / 14, wp = rem % 14;
    const float* b = in + (size_t)nc*LSP + tp*2*784 + hp*2*28 + wp*2;
    float m = b[0];
    m = fmaxf(m, b[1]);   m = fmaxf(m, b[28]);  m = fmaxf(m, b[29]);
    m = fmaxf(m, b[784]); m = fmaxf(m, b[785]); m = fmaxf(m, b[812]); m = fmaxf(m, b[813]);
    out[id] = m;
}

// ---------------------------------------------------------------------------
// K3: scores for one query chunk. s[q][k] = sum_c qf[n][c][qbase+q] * kp[n][c][k]
// BM=32 (q), BN=64 (k, masked at 784), K=64 via BK=32.
// ---------------------------------------------------------------------------
__global__ __launch_bounds__(256) void scores_kernel(
    const float* __restrict__ qf, const float* __restrict__ kp,
    float* __restrict__ beta, int qbase)
{
    int t  = threadIdx.x;
    int k0 = blockIdx.x * 64;
    int q0 = blockIdx.y * 32;
    int n  = blockIdx.z;
    __shared__ float As[32][32];   // [c][q]
    __shared__ float Bs[32][64];   // [c][k]
    int tx = t & 15, ty = t >> 4;
    float acc[2][4] = {};

    for (int kb = 0; kb < CQ; kb += 32) {
        #pragma unroll
        for (int i = 0; i < 4; i++) {      // A: 32q x 32c
            int idx = i*256 + t;
            int q = idx & 31, cc = idx >> 5;
            As[cc][q] = qf[((size_t)(n*CQ + kb + cc))*LSP + qbase + q0 + q];
        }
        #pragma unroll
        for (int i = 0; i < 8; i++) {      // B: 32c x 64k
            int idx = i*256 + t;
            int j = idx & 63, cc = idx >> 6;
            int kg = k0 + j;
            Bs[cc][j] = (kg < LK) ? kp[((size_t)(n*CQ + kb + cc))*LK + kg] : 0.0f;
        }
        __syncthreads();
        #pragma unroll
        for (int kk = 0; kk < 32; kk++) {
            float a0 = As[kk][ty*2], a1 = As[kk][ty*2+1];
            #pragma unroll
            for (int j = 0; j < 4; j++) {
                float b = Bs[kk][tx*4+j];
                acc[0][j] += a0*b;
                acc[1][j] += a1*b;
            }
        }
        __syncthreads();
    }
    #pragma unroll
    for (int i = 0; i < 2; i++)
        #pragma unroll
        for (int j = 0; j < 4; j++) {
            int kg = k0 + tx*4 + j;
            if (kg < LK)
                beta[((size_t)(n*QCHUNK + q0 + ty*2 + i))*LK + kg] = acc[i][j];
        }
}

// ---------------------------------------------------------------------------
// K4: row softmax over 784 keys. One wave per row; 4 rows per block.
// ---------------------------------------------------------------------------
__global__ __launch_bounds__(256) void softmax_kernel(float* __restrict__ beta)
{
    int wid = threadIdx.x >> 6, lane = threadIdx.x & 63;
    int row = blockIdx.x * 4 + wid;      // rows: NB*QCHUNK = 6272
    float* r = beta + (size_t)row * LK;
    float v[13];
    float mx = -1e30f;
    #pragma unroll
    for (int i = 0; i < 13; i++) {
        int k = lane + i*64;
        v[i] = (k < LK) ? r[k] : -1e30f;
        mx = fmaxf(mx, v[i]);
    }
    #pragma unroll
    for (int s = 32; s > 0; s >>= 1) mx = fmaxf(mx, __shfl_xor(mx, s));
    float sum = 0.0f;
    #pragma unroll
    for (int i = 0; i < 13; i++) {
        int k = lane + i*64;
        float e = (k < LK) ? __expf(v[i] - mx) : 0.0f;
        v[i] = e;
        sum += e;
    }
    #pragma unroll
    for (int s = 32; s > 0; s >>= 1) sum += __shfl_xor(sum, s);
    float inv = 1.0f / sum;
    #pragma unroll
    for (int i = 0; i < 13; i++) {
        int k = lane + i*64;
        if (k < LK) r[k] = v[i]*inv;
    }
}

// ---------------------------------------------------------------------------
// K5: PV. att[n][cv][qbase+q] = sum_k vp[n][cv][k] * beta[n][q][k]
// BM=64 (cv), BN=32 (q), BK=28 (784 = 28*28, no masking).
// ---------------------------------------------------------------------------
__global__ __launch_bounds__(256) void pv_kernel(
    const float* __restrict__ vp, const float* __restrict__ beta,
    float* __restrict__ att, int qbase)
{
    int t   = threadIdx.x;
    int q0  = blockIdx.x * 32;
    int cv0 = blockIdx.y * 64;
    int n   = blockIdx.z;
    __shared__ float As[28][64];   // [k][cv]
    __shared__ float Bs[28][32];   // [k][q]
    int tx = t & 15, ty = t >> 4;
    float acc[4][2] = {};

    for (int kb = 0; kb < LK; kb += 28) {
        #pragma unroll
        for (int i = 0; i < 7; i++) {      // A: 64cv x 28k
            int idx = i*256 + t;
            int kk = idx % 28, m = idx / 28;
            As[kk][m] = vp[((size_t)(n*CV + cv0 + m))*LK + kb + kk];
        }
        #pragma unroll
        for (int i = 0; i < 4; i++) {      // B: 32q x 28k (896 elems)
            int idx = i*256 + t;
            if (idx < 896) {
                int kk = idx % 28, j = idx / 28;
                Bs[kk][j] = beta[((size_t)(n*QCHUNK + q0 + j))*LK + kb + kk];
            }
        }
        __syncthreads();
        #pragma unroll
        for (int kk = 0; kk < 28; kk++) {
            float b0 = Bs[kk][tx*2], b1 = Bs[kk][tx*2+1];
            #pragma unroll
            for (int i = 0; i < 4; i++) {
                float a = As[kk][ty*4+i];
                acc[i][0] += a*b0;
                acc[i][1] += a*b1;
            }
        }
        __syncthreads();
    }
    #pragma unroll
    for (int i = 0; i < 4; i++)
        #pragma unroll
        for (int j = 0; j < 2; j++)
            att[((size_t)(n*CV + cv0 + ty*4 + i))*LSP + qbase + q0 + tx*2 + j] = acc[i][j];
}

// ---------------------------------------------------------------------------
// K6: Z projection + residual. out = y * (Wz @ att) + x
// BM=64 (c), BN=64 (p), BK=32 over CV=256.
// ---------------------------------------------------------------------------
__global__ __launch_bounds__(256) void z_kernel(
    const float* __restrict__ Wz, const float* __restrict__ att,
    const float* __restrict__ x, const float* __restrict__ yp,
    float* __restrict__ out)
{
    int t  = threadIdx.x;
    int p0 = blockIdx.x * 64;
    int c0 = blockIdx.y * 64;
    int n  = blockIdx.z;
    __shared__ float As[32][64];   // [cv][c]
    __shared__ float Bs[32][64];   // [cv][p]
    int tx = t & 15, ty = t >> 4;
    float acc[4][4] = {};

    for (int kb = 0; kb < CV; kb += 32) {
        #pragma unroll
        for (int i = 0; i < 8; i++) {
            int idx = i*256 + t;
            int cc = idx & 31, m = idx >> 5;
            As[cc][m] = Wz[(size_t)(c0+m)*CV + kb + cc];
        }
        #pragma unroll
        for (int i = 0; i < 8; i++) {
            int idx = i*256 + t;
            int j = idx & 63, cc = idx >> 6;
            Bs[cc][j] = att[((size_t)(n*CV + kb + cc))*LSP + p0 + j];
        }
        __syncthreads();
        #pragma unroll
        for (int kk = 0; kk < 32; kk++) {
            float a[4], b[4];
            #pragma unroll
            for (int i = 0; i < 4; i++) a[i] = As[kk][ty*4+i];
            #pragma unroll
            for (int j = 0; j < 4; j++) b[j] = Bs[kk][tx*4+j];
            #pragma unroll
            for (int i = 0; i < 4; i++)
                #pragma unroll
                for (int j = 0; j < 4; j++)
                    acc[i][j] += a[i]*b[j];
        }
        __syncthreads();
    }
    float yv = *yp;
    #pragma unroll
    for (int i = 0; i < 4; i++)
        #pragma unroll
        for (int j = 0; j < 4; j++) {
            size_t idx = ((size_t)(n*CIN + c0 + ty*4 + i))*LSP + p0 + tx*4 + j;
            out[idx] = yv * acc[i][j] + x[idx];
        }
}

// ---------------------------------------------------------------------------
// Workspace layout (floats), total 17,059,840 f = 68.2 MB:
//   qf    [4][64][6272]   @ 0          (1,605,632)
//   kp    [4][64][784]    @ 1,605,632  (200,704)
//   vp    [4][256][784]   @ 1,806,336  (802,816)
//   att   [4][256][6272]  @ 2,609,152  (6,422,528)
//   kfull [4][64][6272]   @ 9,031,680  (1,605,632)   } beta chunk aliases this
//   vfull [4][256][6272]  @ 10,637,312 (6,422,528)   } region after pooling
//   beta  [4][1568][784]  @ 9,031,680  (4,917,248 <= 8,028,160) OK
// ---------------------------------------------------------------------------
extern "C" void kernel_launch(void* const* d_in, const int* in_sizes, int n_in,
                              void* d_out, int out_size, void* d_ws, size_t ws_size,
                              hipStream_t stream)
{
    const float* x  = (const float*)d_in[0];
    const float* Wq = (const float*)d_in[1];
    const float* Wk = (const float*)d_in[2];
    const float* Wv = (const float*)d_in[3];
    const float* Wz = (const float*)d_in[4];
    const float* y  = (const float*)d_in[5];
    float* out = (float*)d_out;
    float* ws  = (float*)d_ws;

    float* qf    = ws;
    float* kp    = qf  + (size_t)1605632;
    float* vp    = kp  + (size_t)200704;
    float* att   = vp  + (size_t)802816;
    float* kfull = att + (size_t)6422528;
    float* vfull = kfull + (size_t)1605632;
    float* beta  = kfull;   // alias: kfull/vfull dead after pooling

    qkv_kernel<<<dim3(98, 6, 4), 256, 0, stream>>>(x, Wq, Wk, Wv, qf, kfull, vfull);
    pool_kernel<<<dim3((NB*CQ*LK + 255)/256), 256, 0, stream>>>(kfull, kp, NB*CQ);
    pool_kernel<<<dim3((NB*CV*LK + 255)/256), 256, 0, stream>>>(vfull, vp, NB*CV);

    for (int qc = 0; qc < 4; qc++) {
        int qbase = qc * QCHUNK;
        scores_kernel<<<dim3(13, 49, 4), 256, 0, stream>>>(qf, kp, beta, qbase);
        softmax_kernel<<<dim3(NB*QCHUNK/4), 256, 0, stream>>>(beta);
        pv_kernel<<<dim3(49, 4, 4), 256, 0, stream>>>(vp, beta, att, qbase);
    }
    z_kernel<<<dim3(98, 8, 4), 256, 0, stream>>>(Wz, att, x, y, out);
}

// Round 2
// 247.374 us; speedup vs baseline: 4.9745x; 4.9745x over previous
//
#include <hip/hip_runtime.h>
#include <hip/hip_bf16.h>

// Problem constants
#define LSP  6272   // 8*28*28 spatial
#define LK   784    // 4*14*14 pooled spatial
#define CIN  512
#define CQo  64
#define CVo  256
#define NB   4

typedef __bf16  bf16x8 __attribute__((ext_vector_type(8)));
typedef __bf16  bf16x4 __attribute__((ext_vector_type(4)));
typedef float   f32x4  __attribute__((ext_vector_type(4)));

#define LDT  40   // padded LDS row (bf16 elems) for K=32 tiles: 80 B = 16*5
#define LDS2 72   // padded LDS row for K=64 tiles: 144 B = 16*9

// ---------------------------------------------------------------------------
// K0: transpose+convert x [n][c][p] fp32 -> xT [n][p][c] bf16
// ---------------------------------------------------------------------------
__global__ __launch_bounds__(256) void xt_kernel(const float* __restrict__ x,
                                                 __bf16* __restrict__ xT)
{
    __shared__ __attribute__((aligned(16))) __bf16 tile[64][68];
    int t = threadIdx.x;
    int p0 = blockIdx.x * 64, c0 = blockIdx.y * 64, n = blockIdx.z;
    #pragma unroll
    for (int i = 0; i < 4; i++) {
        int idx = i * 256 + t;              // float4 units, 1024 total
        int c = idx >> 4, p4 = (idx & 15) * 4;
        const float4 v = *reinterpret_cast<const float4*>(
            &x[((size_t)(n * CIN + c0 + c)) * LSP + p0 + p4]);
        tile[p4 + 0][c] = (__bf16)v.x;
        tile[p4 + 1][c] = (__bf16)v.y;
        tile[p4 + 2][c] = (__bf16)v.z;
        tile[p4 + 3][c] = (__bf16)v.w;
    }
    __syncthreads();
    #pragma unroll
    for (int i = 0; i < 4; i++) {
        int idx = i * 256 + t;
        int p = idx >> 4, c4 = (idx & 15) * 4;
        bf16x4 o;
        o[0] = tile[p][c4 + 0]; o[1] = tile[p][c4 + 1];
        o[2] = tile[p][c4 + 2]; o[3] = tile[p][c4 + 3];
        *reinterpret_cast<bf16x4*>(&xT[((size_t)(n * LSP + p0 + p)) * CIN + c0 + c4]) = o;
    }
}

// ---------------------------------------------------------------------------
// K0b: weight prep. Wqkv bf16 [384][512] (Wq,Wk,Wv stacked); Wz bf16 [512][256]
// ---------------------------------------------------------------------------
__global__ void wprep_kernel(const float* __restrict__ Wq, const float* __restrict__ Wk,
                             const float* __restrict__ Wv, const float* __restrict__ Wz,
                             __bf16* __restrict__ Wqkv, __bf16* __restrict__ Wzb)
{
    int idx = blockIdx.x * 256 + threadIdx.x;
    if (idx < 384 * 512) {
        int o = idx >> 9;
        float v = (o < 64) ? Wq[idx] : (o < 128) ? Wk[idx - 64 * 512] : Wv[idx - 128 * 512];
        Wqkv[idx] = (__bf16)v;
    }
    if (idx < 512 * 256) Wzb[idx] = (__bf16)Wz[idx];
}

// ---------------------------------------------------------------------------
// K1: QKV MFMA GEMM. out[o][p] = sum_c Wqkv[o][c] * xT[n][p][c]
// Block 256 thr = 4 waves (2x2 of 64x64), tile 128x128, K-step 32.
// m-tile 0 (o 0..127): write qT/kT transposed [n][p][64] bf16.
// m-tiles 1,2 (o 128..383): write vconv [n][cv][p] bf16.
// ---------------------------------------------------------------------------
__global__ __launch_bounds__(256) void qkv_gemm(const __bf16* __restrict__ Wqkv,
                                                const __bf16* __restrict__ xT,
                                                __bf16* __restrict__ qT,
                                                __bf16* __restrict__ kT,
                                                __bf16* __restrict__ vconv)
{
    __shared__ __attribute__((aligned(16))) __bf16 As[128 * LDT];
    __shared__ __attribute__((aligned(16))) __bf16 Bs[128 * LDT];
    int t = threadIdx.x;
    int p0 = blockIdx.x * 128;
    int m0 = blockIdx.y * 128;
    int n  = blockIdx.z;
    int lane = t & 63, wid = t >> 6;
    int wm = wid >> 1, wn = wid & 1;
    int lm = lane & 15, lk = lane >> 4;

    f32x4 acc[4][4] = {};

    for (int kb = 0; kb < CIN; kb += 32) {
        #pragma unroll
        for (int i = 0; i < 2; i++) {
            int idx = i * 2048 + t * 8;
            int r = idx >> 5, k8 = idx & 31;
            uint4 va = *reinterpret_cast<const uint4*>(&Wqkv[(size_t)(m0 + r) * CIN + kb + k8]);
            *reinterpret_cast<uint4*>(&As[r * LDT + k8]) = va;
            uint4 vb = *reinterpret_cast<const uint4*>(&xT[((size_t)(n * LSP + p0 + r)) * CIN + kb + k8]);
            *reinterpret_cast<uint4*>(&Bs[r * LDT + k8]) = vb;
        }
        __syncthreads();
        bf16x8 a[4], b[4];
        #pragma unroll
        for (int mi = 0; mi < 4; mi++)
            a[mi] = *reinterpret_cast<const bf16x8*>(&As[(wm * 64 + mi * 16 + lm) * LDT + lk * 8]);
        #pragma unroll
        for (int ni = 0; ni < 4; ni++)
            b[ni] = *reinterpret_cast<const bf16x8*>(&Bs[(wn * 64 + ni * 16 + lm) * LDT + lk * 8]);
        #pragma unroll
        for (int mi = 0; mi < 4; mi++)
            #pragma unroll
            for (int ni = 0; ni < 4; ni++)
                acc[mi][ni] = __builtin_amdgcn_mfma_f32_16x16x32_bf16(a[mi], b[ni], acc[mi][ni], 0, 0, 0);
        __syncthreads();
    }

    #pragma unroll
    for (int mi = 0; mi < 4; mi++) {
        int mloc = wm * 64 + mi * 16 + lk * 4;
        #pragma unroll
        for (int ni = 0; ni < 4; ni++) {
            int p = p0 + wn * 64 + ni * 16 + lm;
            if (m0 == 0) {
                bf16x4 o;
                o[0] = (__bf16)acc[mi][ni][0]; o[1] = (__bf16)acc[mi][ni][1];
                o[2] = (__bf16)acc[mi][ni][2]; o[3] = (__bf16)acc[mi][ni][3];
                if (mloc < 64)
                    *reinterpret_cast<bf16x4*>(&qT[((size_t)(n * LSP + p)) * 64 + mloc]) = o;
                else
                    *reinterpret_cast<bf16x4*>(&kT[((size_t)(n * LSP + p)) * 64 + (mloc - 64)]) = o;
            } else {
                int cv = m0 - 128 + mloc;
                #pragma unroll
                for (int r = 0; r < 4; r++)
                    vconv[((size_t)(n * CVo + cv + r)) * LSP + p] = (__bf16)acc[mi][ni][r];
            }
        }
    }
}

// ---------------------------------------------------------------------------
// K2a: pool kT [n][p][64] -> kpT [n][784][64] (max over 8 spatial positions)
// One wave per pooled row; lane = channel.
// ---------------------------------------------------------------------------
__global__ __launch_bounds__(256) void poolk_kernel(const __bf16* __restrict__ kT,
                                                    __bf16* __restrict__ kpT)
{
    int wid = threadIdx.x >> 6, lane = threadIdx.x & 63;
    int row = blockIdx.x * 4 + wid;          // 0 .. NB*LK-1
    int n = row / LK, pk = row % LK;
    int tp = pk / 196, rem = pk % 196, hp = rem / 14, wp = rem % 14;
    const __bf16* b = kT + ((size_t)n * LSP + tp * 2 * 784 + hp * 2 * 28 + wp * 2) * 64 + lane;
    float m =        (float)b[0];
    m = fmaxf(m, (float)b[64]);
    m = fmaxf(m, (float)b[28 * 64]);
    m = fmaxf(m, (float)b[29 * 64]);
    m = fmaxf(m, (float)b[784 * 64]);
    m = fmaxf(m, (float)b[785 * 64]);
    m = fmaxf(m, (float)b[812 * 64]);
    m = fmaxf(m, (float)b[813 * 64]);
    kpT[(size_t)row * 64 + lane] = (__bf16)m;
}

// ---------------------------------------------------------------------------
// K2b: pool vconv [n][cv][p] -> vp [n][cv][784]
// ---------------------------------------------------------------------------
__global__ void poolv_kernel(const __bf16* __restrict__ vconv, __bf16* __restrict__ vp)
{
    int id = blockIdx.x * 256 + threadIdx.x;
    if (id >= NB * CVo * LK) return;
    int nc = id / LK, pk = id % LK;
    int tp = pk / 196, rem = pk % 196, hp = rem / 14, wp = rem % 14;
    const __bf16* b = vconv + (size_t)nc * LSP + tp * 2 * 784 + hp * 2 * 28 + wp * 2;
    float m =        (float)b[0];
    m = fmaxf(m, (float)b[1]);   m = fmaxf(m, (float)b[28]);  m = fmaxf(m, (float)b[29]);
    m = fmaxf(m, (float)b[784]); m = fmaxf(m, (float)b[785]); m = fmaxf(m, (float)b[812]); m = fmaxf(m, (float)b[813]);
    vp[id] = (__bf16)m;
}

// ---------------------------------------------------------------------------
// K3: scores MFMA GEMM. sc[n][q][k] = sum_c qT[n][q][c] * kpT[n][k][c], bf16 out.
// K=64 staged entirely; tile 128(q) x 128(k), mask k >= 784.
// ---------------------------------------------------------------------------
__global__ __launch_bounds__(256) void scores_gemm(const __bf16* __restrict__ qT,
                                                   const __bf16* __restrict__ kpT,
                                                   __bf16* __restrict__ sc)
{
    __shared__ __attribute__((aligned(16))) __bf16 As[128 * LDS2];
    __shared__ __attribute__((aligned(16))) __bf16 Bs[128 * LDS2];
    int t = threadIdx.x;
    int k0 = blockIdx.x * 128;
    int q0 = blockIdx.y * 128;
    int n  = blockIdx.z;
    int lane = t & 63, wid = t >> 6;
    int wm = wid >> 1, wn = wid & 1;
    int lm = lane & 15, lk = lane >> 4;

    #pragma unroll
    for (int i = 0; i < 4; i++) {
        int idx = i * 2048 + t * 8;
        int r = idx >> 6, k8 = idx & 63;
        *reinterpret_cast<uint4*>(&As[r * LDS2 + k8]) =
            *reinterpret_cast<const uint4*>(&qT[((size_t)(n * LSP + q0 + r)) * 64 + k8]);
        uint4 vb = {0u, 0u, 0u, 0u};
        if (k0 + r < LK)
            vb = *reinterpret_cast<const uint4*>(&kpT[((size_t)(n * LK + k0 + r)) * 64 + k8]);
        *reinterpret_cast<uint4*>(&Bs[r * LDS2 + k8]) = vb;
    }
    __syncthreads();

    f32x4 acc[4][4] = {};
    #pragma unroll
    for (int ks = 0; ks < 2; ks++) {
        bf16x8 a[4], b[4];
        #pragma unroll
        for (int mi = 0; mi < 4; mi++)
            a[mi] = *reinterpret_cast<const bf16x8*>(&As[(wm * 64 + mi * 16 + lm) * LDS2 + ks * 32 + lk * 8]);
        #pragma unroll
        for (int ni = 0; ni < 4; ni++)
            b[ni] = *reinterpret_cast<const bf16x8*>(&Bs[(wn * 64 + ni * 16 + lm) * LDS2 + ks * 32 + lk * 8]);
        #pragma unroll
        for (int mi = 0; mi < 4; mi++)
            #pragma unroll
            for (int ni = 0; ni < 4; ni++)
                acc[mi][ni] = __builtin_amdgcn_mfma_f32_16x16x32_bf16(a[mi], b[ni], acc[mi][ni], 0, 0, 0);
    }

    #pragma unroll
    for (int mi = 0; mi < 4; mi++) {
        int q = q0 + wm * 64 + mi * 16 + lk * 4;
        #pragma unroll
        for (int ni = 0; ni < 4; ni++) {
            int k = k0 + wn * 64 + ni * 16 + lm;
            if (k < LK) {
                #pragma unroll
                for (int r = 0; r < 4; r++)
                    sc[((size_t)(n * LSP + q + r)) * LK + k] = (__bf16)acc[mi][ni][r];
            }
        }
    }
}

// ---------------------------------------------------------------------------
// K4: row softmax over 784 keys, bf16 in/out, in-place. Wave per row.
// ---------------------------------------------------------------------------
__global__ __launch_bounds__(256) void softmax_kernel(__bf16* __restrict__ sc)
{
    int wid = threadIdx.x >> 6, lane = threadIdx.x & 63;
    size_t row = (size_t)blockIdx.x * 4 + wid;   // NB*LSP rows
    __bf16* r = sc + row * LK;
    float v[13];
    float mx = -1e30f;
    #pragma unroll
    for (int i = 0; i < 13; i++) {
        int k = lane + i * 64;
        v[i] = (k < LK) ? (float)r[k] : -1e30f;
        mx = fmaxf(mx, v[i]);
    }
    #pragma unroll
    for (int s = 32; s > 0; s >>= 1) mx = fmaxf(mx, __shfl_xor(mx, s));
    float sum = 0.0f;
    #pragma unroll
    for (int i = 0; i < 13; i++) {
        float e = (lane + i * 64 < LK) ? __expf(v[i] - mx) : 0.0f;
        v[i] = e;
        sum += e;
    }
    #pragma unroll
    for (int s = 32; s > 0; s >>= 1) sum += __shfl_xor(sum, s);
    float inv = 1.0f / sum;
    #pragma unroll
    for (int i = 0; i < 13; i++) {
        int k = lane + i * 64;
        if (k < LK) r[k] = (__bf16)(v[i] * inv);
    }
}

// ---------------------------------------------------------------------------
// K5: PV MFMA GEMM. attT[n][q][cv] = sum_k vp[n][cv][k] * sc[n][q][k]
// M=cv(256), N=q(6272), K=784 (step 32, masked tail).
// ---------------------------------------------------------------------------
__global__ __launch_bounds__(256) void pv_gemm(const __bf16* __restrict__ vp,
                                               const __bf16* __restrict__ sc,
                                               __bf16* __restrict__ attT)
{
    __shared__ __attribute__((aligned(16))) __bf16 As[128 * LDT];
    __shared__ __attribute__((aligned(16))) __bf16 Bs[128 * LDT];
    int t = threadIdx.x;
    int q0 = blockIdx.x * 128;
    int m0 = blockIdx.y * 128;   // cv tile
    int n  = blockIdx.z;
    int lane = t & 63, wid = t >> 6;
    int wm = wid >> 1, wn = wid & 1;
    int lm = lane & 15, lk = lane >> 4;

    f32x4 acc[4][4] = {};

    for (int kb = 0; kb < 800; kb += 32) {
        #pragma unroll
        for (int i = 0; i < 2; i++) {
            int idx = i * 2048 + t * 8;
            int r = idx >> 5, k8 = idx & 31;
            uint4 va = {0u, 0u, 0u, 0u}, vb = {0u, 0u, 0u, 0u};
            if (kb + k8 < LK) {
                va = *reinterpret_cast<const uint4*>(&vp[((size_t)(n * CVo + m0 + r)) * LK + kb + k8]);
                vb = *reinterpret_cast<const uint4*>(&sc[((size_t)(n * LSP + q0 + r)) * LK + kb + k8]);
            }
            *reinterpret_cast<uint4*>(&As[r * LDT + k8]) = va;
            *reinterpret_cast<uint4*>(&Bs[r * LDT + k8]) = vb;
        }
        __syncthreads();
        bf16x8 a[4], b[4];
        #pragma unroll
        for (int mi = 0; mi < 4; mi++)
            a[mi] = *reinterpret_cast<const bf16x8*>(&As[(wm * 64 + mi * 16 + lm) * LDT + lk * 8]);
        #pragma unroll
        for (int ni = 0; ni < 4; ni++)
            b[ni] = *reinterpret_cast<const bf16x8*>(&Bs[(wn * 64 + ni * 16 + lm) * LDT + lk * 8]);
        #pragma unroll
        for (int mi = 0; mi < 4; mi++)
            #pragma unroll
            for (int ni = 0; ni < 4; ni++)
                acc[mi][ni] = __builtin_amdgcn_mfma_f32_16x16x32_bf16(a[mi], b[ni], acc[mi][ni], 0, 0, 0);
        __syncthreads();
    }

    #pragma unroll
    for (int mi = 0; mi < 4; mi++) {
        int cvb = m0 + wm * 64 + mi * 16 + lk * 4;
        #pragma unroll
        for (int ni = 0; ni < 4; ni++) {
            int q = q0 + wn * 64 + ni * 16 + lm;
            bf16x4 o;
            o[0] = (__bf16)acc[mi][ni][0]; o[1] = (__bf16)acc[mi][ni][1];
            o[2] = (__bf16)acc[mi][ni][2]; o[3] = (__bf16)acc[mi][ni][3];
            *reinterpret_cast<bf16x4*>(&attT[((size_t)(n * LSP + q)) * CVo + cvb]) = o;
        }
    }
}

// ---------------------------------------------------------------------------
// K6: Z MFMA GEMM + residual. out[n][c][p] = y * sum_cv Wz[c][cv]*attT[n][p][cv] + x
// M=c(512), N=p(6272), K=256.
// ---------------------------------------------------------------------------
__global__ __launch_bounds__(256) void z_gemm(const __bf16* __restrict__ Wzb,
                                              const __bf16* __restrict__ attT,
                                              const float* __restrict__ x,
                                              const float* __restrict__ yp,
                                              float* __restrict__ out)
{
    __shared__ __attribute__((aligned(16))) __bf16 As[128 * LDT];
    __shared__ __attribute__((aligned(16))) __bf16 Bs[128 * LDT];
    int t = threadIdx.x;
    int p0 = blockIdx.x * 128;
    int m0 = blockIdx.y * 128;
    int n  = blockIdx.z;
    int lane = t & 63, wid = t >> 6;
    int wm = wid >> 1, wn = wid & 1;
    int lm = lane & 15, lk = lane >> 4;

    f32x4 acc[4][4] = {};

    for (int kb = 0; kb < CVo; kb += 32) {
        #pragma unroll
        for (int i = 0; i < 2; i++) {
            int idx = i * 2048 + t * 8;
            int r = idx >> 5, k8 = idx & 31;
            uint4 va = *reinterpret_cast<const uint4*>(&Wzb[(size_t)(m0 + r) * CVo + kb + k8]);
            *reinterpret_cast<uint4*>(&As[r * LDT + k8]) = va;
            uint4 vb = *reinterpret_cast<const uint4*>(&attT[((size_t)(n * LSP + p0 + r)) * CVo + kb + k8]);
            *reinterpret_cast<uint4*>(&Bs[r * LDT + k8]) = vb;
        }
        __syncthreads();
        bf16x8 a[4], b[4];
        #pragma unroll
        for (int mi = 0; mi < 4; mi++)
            a[mi] = *reinterpret_cast<const bf16x8*>(&As[(wm * 64 + mi * 16 + lm) * LDT + lk * 8]);
        #pragma unroll
        for (int ni = 0; ni < 4; ni++)
            b[ni] = *reinterpret_cast<const bf16x8*>(&Bs[(wn * 64 + ni * 16 + lm) * LDT + lk * 8]);
        #pragma unroll
        for (int mi = 0; mi < 4; mi++)
            #pragma unroll
            for (int ni = 0; ni < 4; ni++)
                acc[mi][ni] = __builtin_amdgcn_mfma_f32_16x16x32_bf16(a[mi], b[ni], acc[mi][ni], 0, 0, 0);
        __syncthreads();
    }

    float yv = yp[0];
    #pragma unroll
    for (int mi = 0; mi < 4; mi++) {
        int c = m0 + wm * 64 + mi * 16 + lk * 4;
        #pragma unroll
        for (int ni = 0; ni < 4; ni++) {
            int p = p0 + wn * 64 + ni * 16 + lm;
            #pragma unroll
            for (int r = 0; r < 4; r++) {
                size_t o = ((size_t)(n * CIN + c + r)) * LSP + p;
                out[o] = yv * acc[mi][ni][r] + x[o];
            }
        }
    }
}

// ---------------------------------------------------------------------------
// Workspace layout (bf16 units = 2 B). Total 60,465,152 B.
//   xT    [4][6272][512] @ 0            (12,845,056)  } sc [4][6272][784]
//   kT    [4][6272][64]  @ 12,845,056   ( 1,605,632)  }  (19,668,992) aliases
//   vconv [4][256][6272] @ 14,450,688   ( 6,422,528)  }  this region
//   qT    [4][6272][64]  @ 20,873,216   ( 1,605,632)
//   kpT   [4][784][64]   @ 22,478,848   (   200,704)
//   vp    [4][256][784]  @ 22,679,552   (   802,816)
//   attT  [4][6272][256] @ 23,482,368   ( 6,422,528)
//   Wqkv  [384][512]     @ 29,904,896   (   196,608)
//   Wzb   [512][256]     @ 30,101,504   (   131,072)
// ---------------------------------------------------------------------------
extern "C" void kernel_launch(void* const* d_in, const int* in_sizes, int n_in,
                              void* d_out, int out_size, void* d_ws, size_t ws_size,
                              hipStream_t stream)
{
    const float* x  = (const float*)d_in[0];
    const float* Wq = (const float*)d_in[1];
    const float* Wk = (const float*)d_in[2];
    const float* Wv = (const float*)d_in[3];
    const float* Wz = (const float*)d_in[4];
    const float* y  = (const float*)d_in[5];
    float* out = (float*)d_out;
    __bf16* ws = (__bf16*)d_ws;

    __bf16* xT    = ws;
    __bf16* kT    = ws + (size_t)12845056;
    __bf16* vconv = ws + (size_t)14450688;
    __bf16* sc    = ws;                       // alias xT+kT+vconv (dead by then)
    __bf16* qT    = ws + (size_t)20873216;
    __bf16* kpT   = ws + (size_t)22478848;
    __bf16* vp    = ws + (size_t)22679552;
    __bf16* attT  = ws + (size_t)23482368;
    __bf16* Wqkv  = ws + (size_t)29904896;
    __bf16* Wzb   = ws + (size_t)30101504;

    xt_kernel   <<<dim3(98, 8, 4), 256, 0, stream>>>(x, xT);
    wprep_kernel<<<dim3(768), 256, 0, stream>>>(Wq, Wk, Wv, Wz, Wqkv, Wzb);
    qkv_gemm    <<<dim3(49, 3, 4), 256, 0, stream>>>(Wqkv, xT, qT, kT, vconv);
    poolk_kernel<<<dim3(784), 256, 0, stream>>>(kT, kpT);
    poolv_kernel<<<dim3(3136), 256, 0, stream>>>(vconv, vp);
    scores_gemm <<<dim3(7, 49, 4), 256, 0, stream>>>(qT, kpT, sc);
    softmax_kernel<<<dim3(6272), 256, 0, stream>>>(sc);
    pv_gemm     <<<dim3(49, 2, 4), 256, 0, stream>>>(vp, sc, attT);
    z_gemm      <<<dim3(49, 4, 4), 256, 0, stream>>>(Wzb, attT, x, y, out);
}

// Round 3
// 244.929 us; speedup vs baseline: 5.0242x; 1.0100x over previous
//
#include <hip/hip_runtime.h>
#include <hip/hip_bf16.h>

// Problem constants
#define LSP  6272   // 8*28*28 spatial
#define LK   784    // 4*14*14 pooled spatial
#define CIN  512
#define CQo  64
#define CVo  256
#define NB   4

typedef __bf16  bf16x8 __attribute__((ext_vector_type(8)));
typedef __bf16  bf16x4 __attribute__((ext_vector_type(4)));
typedef float   f32x4  __attribute__((ext_vector_type(4)));

#define LDT  40   // padded LDS row (bf16 elems) for K=32 tiles: 80 B

// ---------------------------------------------------------------------------
// K0: transpose+convert x [n][c][p] fp32 -> xT [n][p][c] bf16
// ---------------------------------------------------------------------------
__global__ __launch_bounds__(256) void xt_kernel(const float* __restrict__ x,
                                                 __bf16* __restrict__ xT)
{
    __shared__ __attribute__((aligned(16))) __bf16 tile[64][68];
    int t = threadIdx.x;
    int p0 = blockIdx.x * 64, c0 = blockIdx.y * 64, n = blockIdx.z;
    #pragma unroll
    for (int i = 0; i < 4; i++) {
        int idx = i * 256 + t;
        int c = idx >> 4, p4 = (idx & 15) * 4;
        const float4 v = *reinterpret_cast<const float4*>(
            &x[((size_t)(n * CIN + c0 + c)) * LSP + p0 + p4]);
        tile[p4 + 0][c] = (__bf16)v.x;
        tile[p4 + 1][c] = (__bf16)v.y;
        tile[p4 + 2][c] = (__bf16)v.z;
        tile[p4 + 3][c] = (__bf16)v.w;
    }
    __syncthreads();
    #pragma unroll
    for (int i = 0; i < 4; i++) {
        int idx = i * 256 + t;
        int p = idx >> 4, c4 = (idx & 15) * 4;
        bf16x4 o;
        o[0] = tile[p][c4 + 0]; o[1] = tile[p][c4 + 1];
        o[2] = tile[p][c4 + 2]; o[3] = tile[p][c4 + 3];
        *reinterpret_cast<bf16x4*>(&xT[((size_t)(n * LSP + p0 + p)) * CIN + c0 + c4]) = o;
    }
}

// ---------------------------------------------------------------------------
// K0b: weight prep. Wqkv bf16 [384][512]; Wzb bf16 [512][256]
// ---------------------------------------------------------------------------
__global__ void wprep_kernel(const float* __restrict__ Wq, const float* __restrict__ Wk,
                             const float* __restrict__ Wv, const float* __restrict__ Wz,
                             __bf16* __restrict__ Wqkv, __bf16* __restrict__ Wzb)
{
    int idx = blockIdx.x * 256 + threadIdx.x;
    if (idx < 384 * 512) {
        int o = idx >> 9;
        float v = (o < 64) ? Wq[idx] : (o < 128) ? Wk[idx - 64 * 512] : Wv[idx - 128 * 512];
        Wqkv[idx] = (__bf16)v;
    }
    if (idx < 512 * 256) Wzb[idx] = (__bf16)Wz[idx];
}

// ---------------------------------------------------------------------------
// K1: QKV MFMA GEMM (unchanged from round 2).
// ---------------------------------------------------------------------------
__global__ __launch_bounds__(256) void qkv_gemm(const __bf16* __restrict__ Wqkv,
                                                const __bf16* __restrict__ xT,
                                                __bf16* __restrict__ qT,
                                                __bf16* __restrict__ kT,
                                                __bf16* __restrict__ vconv)
{
    __shared__ __attribute__((aligned(16))) __bf16 As[128 * LDT];
    __shared__ __attribute__((aligned(16))) __bf16 Bs[128 * LDT];
    int t = threadIdx.x;
    int p0 = blockIdx.x * 128;
    int m0 = blockIdx.y * 128;
    int n  = blockIdx.z;
    int lane = t & 63, wid = t >> 6;
    int wm = wid >> 1, wn = wid & 1;
    int lm = lane & 15, lk = lane >> 4;

    f32x4 acc[4][4] = {};

    for (int kb = 0; kb < CIN; kb += 32) {
        #pragma unroll
        for (int i = 0; i < 2; i++) {
            int idx = i * 2048 + t * 8;
            int r = idx >> 5, k8 = idx & 31;
            *reinterpret_cast<uint4*>(&As[r * LDT + k8]) =
                *reinterpret_cast<const uint4*>(&Wqkv[(size_t)(m0 + r) * CIN + kb + k8]);
            *reinterpret_cast<uint4*>(&Bs[r * LDT + k8]) =
                *reinterpret_cast<const uint4*>(&xT[((size_t)(n * LSP + p0 + r)) * CIN + kb + k8]);
        }
        __syncthreads();
        bf16x8 a[4], b[4];
        #pragma unroll
        for (int mi = 0; mi < 4; mi++)
            a[mi] = *reinterpret_cast<const bf16x8*>(&As[(wm * 64 + mi * 16 + lm) * LDT + lk * 8]);
        #pragma unroll
        for (int ni = 0; ni < 4; ni++)
            b[ni] = *reinterpret_cast<const bf16x8*>(&Bs[(wn * 64 + ni * 16 + lm) * LDT + lk * 8]);
        #pragma unroll
        for (int mi = 0; mi < 4; mi++)
            #pragma unroll
            for (int ni = 0; ni < 4; ni++)
                acc[mi][ni] = __builtin_amdgcn_mfma_f32_16x16x32_bf16(a[mi], b[ni], acc[mi][ni], 0, 0, 0);
        __syncthreads();
    }

    #pragma unroll
    for (int mi = 0; mi < 4; mi++) {
        int mloc = wm * 64 + mi * 16 + lk * 4;
        #pragma unroll
        for (int ni = 0; ni < 4; ni++) {
            int p = p0 + wn * 64 + ni * 16 + lm;
            if (m0 == 0) {
                bf16x4 o;
                o[0] = (__bf16)acc[mi][ni][0]; o[1] = (__bf16)acc[mi][ni][1];
                o[2] = (__bf16)acc[mi][ni][2]; o[3] = (__bf16)acc[mi][ni][3];
                if (mloc < 64)
                    *reinterpret_cast<bf16x4*>(&qT[((size_t)(n * LSP + p)) * 64 + mloc]) = o;
                else
                    *reinterpret_cast<bf16x4*>(&kT[((size_t)(n * LSP + p)) * 64 + (mloc - 64)]) = o;
            } else {
                int cv = m0 - 128 + mloc;
                #pragma unroll
                for (int r = 0; r < 4; r++)
                    vconv[((size_t)(n * CVo + cv + r)) * LSP + p] = (__bf16)acc[mi][ni][r];
            }
        }
    }
}

// ---------------------------------------------------------------------------
// K2a: pool kT [n][p][64] -> kpT [n][784][64]
// ---------------------------------------------------------------------------
__global__ __launch_bounds__(256) void poolk_kernel(const __bf16* __restrict__ kT,
                                                    __bf16* __restrict__ kpT)
{
    int wid = threadIdx.x >> 6, lane = threadIdx.x & 63;
    int row = blockIdx.x * 4 + wid;
    int n = row / LK, pk = row % LK;
    int tp = pk / 196, rem = pk % 196, hp = rem / 14, wp = rem % 14;
    const __bf16* b = kT + ((size_t)n * LSP + tp * 2 * 784 + hp * 2 * 28 + wp * 2) * 64 + lane;
    float m =        (float)b[0];
    m = fmaxf(m, (float)b[64]);
    m = fmaxf(m, (float)b[28 * 64]);
    m = fmaxf(m, (float)b[29 * 64]);
    m = fmaxf(m, (float)b[784 * 64]);
    m = fmaxf(m, (float)b[785 * 64]);
    m = fmaxf(m, (float)b[812 * 64]);
    m = fmaxf(m, (float)b[813 * 64]);
    kpT[(size_t)row * 64 + lane] = (__bf16)m;
}

// ---------------------------------------------------------------------------
// K2b: pool vconv [n][cv][p] -> vp [n][cv][784]
// ---------------------------------------------------------------------------
__global__ void poolv_kernel(const __bf16* __restrict__ vconv, __bf16* __restrict__ vp)
{
    int id = blockIdx.x * 256 + threadIdx.x;
    if (id >= NB * CVo * LK) return;
    int nc = id / LK, pk = id % LK;
    int tp = pk / 196, rem = pk % 196, hp = rem / 14, wp = rem % 14;
    const __bf16* b = vconv + (size_t)nc * LSP + tp * 2 * 784 + hp * 2 * 28 + wp * 2;
    float m =        (float)b[0];
    m = fmaxf(m, (float)b[1]);   m = fmaxf(m, (float)b[28]);  m = fmaxf(m, (float)b[29]);
    m = fmaxf(m, (float)b[784]); m = fmaxf(m, (float)b[785]); m = fmaxf(m, (float)b[812]); m = fmaxf(m, (float)b[813]);
    vp[id] = (__bf16)m;
}

// ---------------------------------------------------------------------------
// K3: fused flash attention: scores + online softmax + PV.
// Block = 4 waves, q-tile 64, k-tiles of 128 (7 tiles, last masked at 784).
// Wave w: S-phase computes S[16q x 128k] for q rows w*16..w*16+15;
//         PV-phase computes O[cv 64-slice w][all 64 q].
// K, V frags read direct from global (L2-resident); P via XOR-swizzled LDS.
// ---------------------------------------------------------------------------
__global__ __launch_bounds__(256) void flash_kernel(
    const __bf16* __restrict__ qT, const __bf16* __restrict__ kpT,
    const __bf16* __restrict__ vp, __bf16* __restrict__ attT)
{
    __shared__ __attribute__((aligned(16))) __bf16 Ps[64 * 128];
    __shared__ float smem_s[64];
    int t = threadIdx.x;
    int lane = t & 63, w = t >> 6;
    int lm = lane & 15, lk = lane >> 4;
    int q0 = blockIdx.x * 64;
    int n  = blockIdx.y;

    // Q fragments in registers: rows q = q0 + w*16 + lm, c = ks*32 + lk*8
    bf16x8 qa[2];
    {
        const __bf16* qrow = &qT[((size_t)(n * LSP + q0 + w * 16 + lm)) * 64 + lk * 8];
        qa[0] = *reinterpret_cast<const bf16x8*>(qrow);
        qa[1] = *reinterpret_cast<const bf16x8*>(qrow + 32);
    }

    f32x4 accO[4][4] = {};
    float m[4], l[4];
    #pragma unroll
    for (int r = 0; r < 4; r++) { m[r] = -1e30f; l[r] = 0.0f; }

    int qrow = w * 16 + lk * 4;   // local q of D rows (+r)

    for (int kt = 0; kt < 7; kt++) {
        int k0 = kt * 128;
        // ---- S phase: S[16q x 128k] per wave ----
        f32x4 accS[8] = {};
        #pragma unroll
        for (int ks = 0; ks < 2; ks++) {
            #pragma unroll
            for (int ni = 0; ni < 8; ni++) {
                int k = k0 + ni * 16 + lm; if (k > 783) k = 783;   // clamp, masked below
                bf16x8 kb = *reinterpret_cast<const bf16x8*>(
                    &kpT[((size_t)(n * LK + k)) * 64 + ks * 32 + lk * 8]);
                accS[ni] = __builtin_amdgcn_mfma_f32_16x16x32_bf16(qa[ks], kb, accS[ni], 0, 0, 0);
            }
        }
        if (kt == 6) {   // mask k >= 784 (only ni=0 valid: k=768..783)
            #pragma unroll
            for (int ni = 1; ni < 8; ni++)
                #pragma unroll
                for (int r = 0; r < 4; r++) accS[ni][r] = -1e30f;
        }
        // ---- online softmax (per q row = qrow + r; k = lm + 16*ni) ----
        float scale[4], lt[4];
        #pragma unroll
        for (int r = 0; r < 4; r++) {
            float v = accS[0][r];
            #pragma unroll
            for (int ni = 1; ni < 8; ni++) v = fmaxf(v, accS[ni][r]);
            #pragma unroll
            for (int d = 1; d < 16; d <<= 1) v = fmaxf(v, __shfl_xor(v, d));
            float mn = fmaxf(m[r], v);
            scale[r] = __expf(m[r] - mn);
            m[r] = mn;
            lt[r] = 0.0f;
        }
        #pragma unroll
        for (int ni = 0; ni < 8; ni++)
            #pragma unroll
            for (int r = 0; r < 4; r++) {
                float p = __expf(accS[ni][r] - m[r]);
                lt[r] += p;
                int q = qrow + r;
                int kl = ni * 16 + lm;
                Ps[q * 128 + (kl ^ ((q & 7) << 3))] = (__bf16)p;   // T2 XOR swizzle
            }
        #pragma unroll
        for (int r = 0; r < 4; r++) {
            #pragma unroll
            for (int d = 1; d < 16; d <<= 1) lt[r] += __shfl_xor(lt[r], d);
            l[r] = l[r] * scale[r] + lt[r];
        }
        if (lm == 0) {
            #pragma unroll
            for (int r = 0; r < 4; r++) smem_s[qrow + r] = scale[r];
        }
        __syncthreads();
        // ---- rescale O by exp(m_old - m_new) of each q column ----
        #pragma unroll
        for (int ni = 0; ni < 4; ni++) {
            float s = smem_s[ni * 16 + lm];
            #pragma unroll
            for (int mi = 0; mi < 4; mi++)
                #pragma unroll
                for (int r = 0; r < 4; r++) accO[mi][ni][r] *= s;
        }
        // ---- PV: A = V[cv rows, k-contig] (global), B = P[q rows] (LDS) ----
        #pragma unroll
        for (int ks = 0; ks < 4; ks++) {
            int kg = k0 + ks * 32 + lk * 8; if (kg > 776) kg = 776;  // clamp (P=0 there)
            bf16x8 pb[4];
            #pragma unroll
            for (int ni = 0; ni < 4; ni++) {
                int q = ni * 16 + lm;
                pb[ni] = *reinterpret_cast<const bf16x8*>(
                    &Ps[q * 128 + ((ks * 32 + lk * 8) ^ ((q & 7) << 3))]);
            }
            #pragma unroll
            for (int mi = 0; mi < 4; mi++) {
                int cv = w * 64 + mi * 16 + lm;
                bf16x8 va = *reinterpret_cast<const bf16x8*>(
                    &vp[((size_t)(n * CVo + cv)) * LK + kg]);
                #pragma unroll
                for (int ni = 0; ni < 4; ni++)
                    accO[mi][ni] = __builtin_amdgcn_mfma_f32_16x16x32_bf16(va, pb[ni], accO[mi][ni], 0, 0, 0);
            }
        }
        __syncthreads();
    }
    // ---- finalize: O /= l, store attT[n][q][cv] bf16 ----
    if (lm == 0) {
        #pragma unroll
        for (int r = 0; r < 4; r++) smem_s[qrow + r] = 1.0f / l[r];
    }
    __syncthreads();
    #pragma unroll
    for (int ni = 0; ni < 4; ni++) {
        float inv = smem_s[ni * 16 + lm];
        int q = q0 + ni * 16 + lm;
        #pragma unroll
        for (int mi = 0; mi < 4; mi++) {
            bf16x4 o;
            #pragma unroll
            for (int r = 0; r < 4; r++) o[r] = (__bf16)(accO[mi][ni][r] * inv);
            *reinterpret_cast<bf16x4*>(
                &attT[((size_t)(n * LSP + q)) * CVo + w * 64 + mi * 16 + lk * 4]) = o;
        }
    }
}

// ---------------------------------------------------------------------------
// K6: Z MFMA GEMM + residual, swapped operands: A=attT(p rows), B=Wz(c rows)
// -> D rows = p -> float4 epilogue on x/out.
// ---------------------------------------------------------------------------
__global__ __launch_bounds__(256) void z_gemm(const __bf16* __restrict__ Wzb,
                                              const __bf16* __restrict__ attT,
                                              const float* __restrict__ x,
                                              const float* __restrict__ yp,
                                              float* __restrict__ out)
{
    __shared__ __attribute__((aligned(16))) __bf16 As[128 * LDT];
    __shared__ __attribute__((aligned(16))) __bf16 Bs[128 * LDT];
    int t = threadIdx.x;
    int p0 = blockIdx.x * 128;
    int c0 = blockIdx.y * 128;
    int n  = blockIdx.z;
    int lane = t & 63, wid = t >> 6;
    int wm = wid >> 1, wn = wid & 1;
    int lm = lane & 15, lk = lane >> 4;

    f32x4 acc[4][4] = {};

    for (int kb = 0; kb < CVo; kb += 32) {
        #pragma unroll
        for (int i = 0; i < 2; i++) {
            int idx = i * 2048 + t * 8;
            int r = idx >> 5, k8 = idx & 31;
            *reinterpret_cast<uint4*>(&As[r * LDT + k8]) =
                *reinterpret_cast<const uint4*>(&attT[((size_t)(n * LSP + p0 + r)) * CVo + kb + k8]);
            *reinterpret_cast<uint4*>(&Bs[r * LDT + k8]) =
                *reinterpret_cast<const uint4*>(&Wzb[(size_t)(c0 + r) * CVo + kb + k8]);
        }
        __syncthreads();
        bf16x8 a[4], b[4];
        #pragma unroll
        for (int mi = 0; mi < 4; mi++)
            a[mi] = *reinterpret_cast<const bf16x8*>(&As[(wm * 64 + mi * 16 + lm) * LDT + lk * 8]);
        #pragma unroll
        for (int ni = 0; ni < 4; ni++)
            b[ni] = *reinterpret_cast<const bf16x8*>(&Bs[(wn * 64 + ni * 16 + lm) * LDT + lk * 8]);
        #pragma unroll
        for (int mi = 0; mi < 4; mi++)
            #pragma unroll
            for (int ni = 0; ni < 4; ni++)
                acc[mi][ni] = __builtin_amdgcn_mfma_f32_16x16x32_bf16(a[mi], b[ni], acc[mi][ni], 0, 0, 0);
        __syncthreads();
    }

    float yv = yp[0];
    #pragma unroll
    for (int mi = 0; mi < 4; mi++) {
        int p = p0 + wm * 64 + mi * 16 + lk * 4;
        #pragma unroll
        for (int ni = 0; ni < 4; ni++) {
            int c = c0 + wn * 64 + ni * 16 + lm;
            size_t o = ((size_t)(n * CIN + c)) * LSP + p;
            const float4 xv = *reinterpret_cast<const float4*>(&x[o]);
            float4 ov;
            ov.x = yv * acc[mi][ni][0] + xv.x;
            ov.y = yv * acc[mi][ni][1] + xv.y;
            ov.z = yv * acc[mi][ni][2] + xv.z;
            ov.w = yv * acc[mi][ni][3] + xv.w;
            *reinterpret_cast<float4*>(&out[o]) = ov;
        }
    }
}

// ---------------------------------------------------------------------------
// Workspace layout (bf16 units = 2 B):
//   xT    [4][6272][512] @ 0            (12,845,056)
//   kT    [4][6272][64]  @ 12,845,056   ( 1,605,632)
//   vconv [4][256][6272] @ 14,450,688   ( 6,422,528)
//   qT    [4][6272][64]  @ 20,873,216   ( 1,605,632)
//   kpT   [4][784][64]   @ 22,478,848   (   200,704)
//   vp    [4][256][784]  @ 22,679,552   (   802,816)
//   attT  [4][6272][256] @ 23,482,368   ( 6,422,528)
//   Wqkv  [384][512]     @ 29,904,896   (   196,608)
//   Wzb   [512][256]     @ 30,101,504   (   131,072)
// ---------------------------------------------------------------------------
extern "C" void kernel_launch(void* const* d_in, const int* in_sizes, int n_in,
                              void* d_out, int out_size, void* d_ws, size_t ws_size,
                              hipStream_t stream)
{
    const float* x  = (const float*)d_in[0];
    const float* Wq = (const float*)d_in[1];
    const float* Wk = (const float*)d_in[2];
    const float* Wv = (const float*)d_in[3];
    const float* Wz = (const float*)d_in[4];
    const float* y  = (const float*)d_in[5];
    float* out = (float*)d_out;
    __bf16* ws = (__bf16*)d_ws;

    __bf16* xT    = ws;
    __bf16* kT    = ws + (size_t)12845056;
    __bf16* vconv = ws + (size_t)14450688;
    __bf16* qT    = ws + (size_t)20873216;
    __bf16* kpT   = ws + (size_t)22478848;
    __bf16* vp    = ws + (size_t)22679552;
    __bf16* attT  = ws + (size_t)23482368;
    __bf16* Wqkv  = ws + (size_t)29904896;
    __bf16* Wzb   = ws + (size_t)30101504;

    xt_kernel    <<<dim3(98, 8, 4), 256, 0, stream>>>(x, xT);
    wprep_kernel <<<dim3(768), 256, 0, stream>>>(Wq, Wk, Wv, Wz, Wqkv, Wzb);
    qkv_gemm     <<<dim3(49, 3, 4), 256, 0, stream>>>(Wqkv, xT, qT, kT, vconv);
    poolk_kernel <<<dim3(784), 256, 0, stream>>>(kT, kpT);
    poolv_kernel <<<dim3(3136), 256, 0, stream>>>(vconv, vp);
    flash_kernel <<<dim3(98, 4), 256, 0, stream>>>(qT, kpT, vp, attT);
    z_gemm       <<<dim3(49, 4, 4), 256, 0, stream>>>(Wzb, attT, x, y, out);
}